// Round 1
// baseline (9318.385 us; speedup 1.0000x reference)
//
#include <hip/hip_runtime.h>
#include <hip/hip_bf16.h>

#define BB 512
#define TT 512
#define DD 128
#define HH 64

__device__ __forceinline__ float sigmoidf_(float x) {
    return 1.0f / (1.0f + __expf(-x));
}
__device__ __forceinline__ float tanhf_(float x) {
    float e = __expf(-2.0f * fabsf(x));
    float t = (1.0f - e) / (1.0f + e);
    return x < 0.0f ? -t : t;
}

// ---------------------------------------------------------------------------
// Encoder: 256 blocks x 256 threads, 2 batch rows per block.
// Thread g (=tid) owns gate row g of Wih_e [256,128] and Whh_e [256,64] in
// registers. Input projection fused into the recurrence (no xp_e in HBM).
// ---------------------------------------------------------------------------
__global__ __launch_bounds__(256, 1)
void enc_kernel(const float* __restrict__ x,      // [B,T,D]
                const float* __restrict__ Wih,    // [256,128]
                const float* __restrict__ Whh,    // [256,64]
                const float* __restrict__ bias_g, // [256]
                float* __restrict__ h_out)        // [B,64]
{
    const int tid = threadIdx.x;      // gate index g in [0,256)
    const int b0  = blockIdx.x * 2;   // two batch rows

    __shared__ __align__(16) float stage[64 * 129];   // weight staging (33 KB)
    __shared__ __align__(16) float x_t[2][DD];
    __shared__ __align__(16) float h_s[2][HH];
    __shared__ __align__(16) float act[2][256];

    float wih[DD];  // 128 regs
    float whh[HH];  // 64 regs

    // ---- stage Wih_e into registers (coalesced global -> padded LDS -> regs)
    for (int ch = 0; ch < 4; ++ch) {
        for (int idx = tid; idx < 64 * 128; idx += 256) {
            int r = idx >> 7, c = idx & 127;
            stage[r * 129 + c] = Wih[(ch * 64 + r) * 128 + c];
        }
        __syncthreads();
        if ((tid >> 6) == ch) {
            int r = tid & 63;
            #pragma unroll
            for (int k = 0; k < DD; ++k) wih[k] = stage[r * 129 + k];
        }
        __syncthreads();
    }
    // ---- stage Whh_e
    for (int ch = 0; ch < 4; ++ch) {
        for (int idx = tid; idx < 64 * 64; idx += 256) {
            int r = idx >> 6, c = idx & 63;
            stage[r * 65 + c] = Whh[(ch * 64 + r) * 64 + c];
        }
        __syncthreads();
        if ((tid >> 6) == ch) {
            int r = tid & 63;
            #pragma unroll
            for (int k = 0; k < HH; ++k) whh[k] = stage[r * 65 + k];
        }
        __syncthreads();
    }

    const float bg = bias_g[tid];
    const int gate = tid >> 6;      // 0:i 1:f 2:g 3:o (wave-uniform)

    // init hidden state
    if (tid < 2 * HH) h_s[tid >> 6][tid & 63] = 0.0f;
    float c_state = 0.0f;           // used by threads tid<128 (r=tid>>6, j=tid&63)
    __syncthreads();

    const float* xrow[2] = { x + (size_t)(b0 + 0) * TT * DD,
                             x + (size_t)(b0 + 1) * TT * DD };

    const float4* x0v = (const float4*)x_t[0];
    const float4* x1v = (const float4*)x_t[1];
    const float4* h0v = (const float4*)h_s[0];
    const float4* h1v = (const float4*)h_s[1];

    for (int t = 0; t < TT; ++t) {
        // load current x rows (coalesced: 128 consecutive floats per row)
        {
            int r = tid >> 7, c = tid & 127;
            x_t[r][c] = xrow[r][(size_t)t * DD + c];
        }
        __syncthreads();

        // gate pre-activation: bg + Wih[g,:] . x_t[r,:] + Whh[g,:] . h[r,:]
        float a0 = bg,  a1 = bg;     // chain A per row
        float e0 = 0.f, e1 = 0.f;    // chain B per row
        #pragma unroll
        for (int k4 = 0; k4 < DD / 4; ++k4) {
            float4 xa = x0v[k4];
            float4 xb = x1v[k4];
            a0 = fmaf(wih[4 * k4 + 0], xa.x, a0);
            e0 = fmaf(wih[4 * k4 + 1], xa.y, e0);
            a0 = fmaf(wih[4 * k4 + 2], xa.z, a0);
            e0 = fmaf(wih[4 * k4 + 3], xa.w, e0);
            a1 = fmaf(wih[4 * k4 + 0], xb.x, a1);
            e1 = fmaf(wih[4 * k4 + 1], xb.y, e1);
            a1 = fmaf(wih[4 * k4 + 2], xb.z, a1);
            e1 = fmaf(wih[4 * k4 + 3], xb.w, e1);
        }
        #pragma unroll
        for (int k4 = 0; k4 < HH / 4; ++k4) {
            float4 ha = h0v[k4];
            float4 hb = h1v[k4];
            a0 = fmaf(whh[4 * k4 + 0], ha.x, a0);
            e0 = fmaf(whh[4 * k4 + 1], ha.y, e0);
            a0 = fmaf(whh[4 * k4 + 2], ha.z, a0);
            e0 = fmaf(whh[4 * k4 + 3], ha.w, e0);
            a1 = fmaf(whh[4 * k4 + 0], hb.x, a1);
            e1 = fmaf(whh[4 * k4 + 1], hb.y, e1);
            a1 = fmaf(whh[4 * k4 + 2], hb.z, a1);
            e1 = fmaf(whh[4 * k4 + 3], hb.w, e1);
        }
        float g0 = a0 + e0;
        float g1 = a1 + e1;

        float v0, v1;
        if (gate == 2) { v0 = tanhf_(g0);    v1 = tanhf_(g1); }
        else           { v0 = sigmoidf_(g0); v1 = sigmoidf_(g1); }
        act[0][tid] = v0;
        act[1][tid] = v1;
        __syncthreads();

        // cell update: threads 0..127 handle (r,j)
        if (tid < 128) {
            int r = tid >> 6, j = tid & 63;
            float iv = act[r][j];
            float fv = act[r][64 + j];
            float gv = act[r][128 + j];
            float ov = act[r][192 + j];
            c_state = fmaf(fv, c_state, iv * gv);
            float hv = ov * tanhf_(c_state);
            h_s[r][j] = hv;
        }
        __syncthreads();
    }

    if (tid < 128) {
        int r = tid >> 6, j = tid & 63;
        h_out[(size_t)(b0 + r) * HH + j] = h_s[r][j];
    }
}

// ---------------------------------------------------------------------------
// Decoder: 256 blocks x 512 threads, 2 batch rows per block.
// Thread g (=tid) owns Whh_d[g,0:128] in registers (256 KB total > LDS).
// Input projection xp_d = b_d + Wih_d @ h_enc computed ONCE (time-invariant:
// decoder input is the tiled encoder hidden state).
// ---------------------------------------------------------------------------
__global__ __launch_bounds__(512, 1)
void dec_kernel(const float* __restrict__ h_enc,  // [B,64]
                const float* __restrict__ Wih,    // [512,64]
                const float* __restrict__ Whh,    // [512,128]
                const float* __restrict__ bias_g, // [512]
                float* __restrict__ out)          // [B,T,D]
{
    const int tid = threadIdx.x;      // gate index g in [0,512)
    const int b0  = blockIdx.x * 2;

    __shared__ __align__(16) float stage[64 * 129];   // 33 KB
    __shared__ __align__(16) float h_s[2][DD];
    __shared__ __align__(16) float act[2][512];
    __shared__ __align__(16) float he[2][HH];

    float whh[DD];   // 128 regs

    // load encoder hidden rows
    if (tid < 2 * HH) he[tid >> 6][tid & 63] = h_enc[(size_t)(b0 + (tid >> 6)) * HH + (tid & 63)];
    __syncthreads();

    // ---- xp_d (time-invariant input projection), staged Wih_d
    float xp0 = bias_g[tid];
    float xp1 = xp0;
    for (int ch = 0; ch < 8; ++ch) {
        for (int idx = tid; idx < 64 * 64; idx += 512) {
            int r = idx >> 6, c = idx & 63;
            stage[r * 65 + c] = Wih[(ch * 64 + r) * 64 + c];
        }
        __syncthreads();
        if ((tid >> 6) == ch) {
            int r = tid & 63;
            #pragma unroll
            for (int k = 0; k < HH; ++k) {
                float w = stage[r * 65 + k];
                xp0 = fmaf(w, he[0][k], xp0);
                xp1 = fmaf(w, he[1][k], xp1);
            }
        }
        __syncthreads();
    }

    // ---- stage Whh_d into registers
    for (int ch = 0; ch < 8; ++ch) {
        for (int idx = tid; idx < 64 * 128; idx += 512) {
            int r = idx >> 7, c = idx & 127;
            stage[r * 129 + c] = Whh[(ch * 64 + r) * 128 + c];
        }
        __syncthreads();
        if ((tid >> 6) == ch) {
            int r = tid & 63;
            #pragma unroll
            for (int k = 0; k < DD; ++k) whh[k] = stage[r * 129 + k];
        }
        __syncthreads();
    }

    const int gate = tid >> 7;   // 0:i 1:f 2:g 3:o (wave-uniform)

    if (tid < 2 * DD) h_s[tid >> 7][tid & 127] = 0.0f;
    float c_state = 0.0f;        // threads tid<256: r=tid>>7, j=tid&127
    __syncthreads();

    const float4* h0v = (const float4*)h_s[0];
    const float4* h1v = (const float4*)h_s[1];

    for (int t = 0; t < TT; ++t) {
        float a0 = xp0, a1 = xp1;
        float e0 = 0.f, e1 = 0.f;
        #pragma unroll
        for (int k4 = 0; k4 < DD / 4; ++k4) {
            float4 ha = h0v[k4];
            float4 hb = h1v[k4];
            a0 = fmaf(whh[4 * k4 + 0], ha.x, a0);
            e0 = fmaf(whh[4 * k4 + 1], ha.y, e0);
            a0 = fmaf(whh[4 * k4 + 2], ha.z, a0);
            e0 = fmaf(whh[4 * k4 + 3], ha.w, e0);
            a1 = fmaf(whh[4 * k4 + 0], hb.x, a1);
            e1 = fmaf(whh[4 * k4 + 1], hb.y, e1);
            a1 = fmaf(whh[4 * k4 + 2], hb.z, a1);
            e1 = fmaf(whh[4 * k4 + 3], hb.w, e1);
        }
        float g0 = a0 + e0;
        float g1 = a1 + e1;

        float v0, v1;
        if (gate == 2) { v0 = tanhf_(g0);    v1 = tanhf_(g1); }
        else           { v0 = sigmoidf_(g0); v1 = sigmoidf_(g1); }
        act[0][tid] = v0;
        act[1][tid] = v1;
        __syncthreads();

        if (tid < 256) {
            int r = tid >> 7, j = tid & 127;
            float iv = act[r][j];
            float fv = act[r][128 + j];
            float gv = act[r][256 + j];
            float ov = act[r][384 + j];
            c_state = fmaf(fv, c_state, iv * gv);
            float hv = ov * tanhf_(c_state);
            h_s[r][j] = hv;
            out[(size_t)(b0 + r) * (TT * DD) + (size_t)t * DD + j] = hv;
        }
        __syncthreads();
    }
}

extern "C" void kernel_launch(void* const* d_in, const int* in_sizes, int n_in,
                              void* d_out, int out_size, void* d_ws, size_t ws_size,
                              hipStream_t stream) {
    const float* x     = (const float*)d_in[0];
    const float* Wih_e = (const float*)d_in[1];
    const float* Whh_e = (const float*)d_in[2];
    const float* b_e   = (const float*)d_in[3];
    const float* Wih_d = (const float*)d_in[4];
    const float* Whh_d = (const float*)d_in[5];
    const float* b_d   = (const float*)d_in[6];
    float* out   = (float*)d_out;
    float* h_enc = (float*)d_ws;   // 512*64 floats = 128 KB scratch

    enc_kernel<<<dim3(BB / 2), dim3(256), 0, stream>>>(x, Wih_e, Whh_e, b_e, h_enc);
    dec_kernel<<<dim3(BB / 2), dim3(512), 0, stream>>>(h_enc, Wih_d, Whh_d, b_d, out);
}

// Round 2
// 1307.132 us; speedup vs baseline: 7.1289x; 7.1289x over previous
//
#include <hip/hip_runtime.h>

#define TT   512
#define DDIM 128   // decoder hidden / input feature dim
#define HDIM 64    // encoder hidden

// ds_swizzle BitMode: lane i receives from lane ((i & and) | or) ^ xor
template<int PAT>
__device__ __forceinline__ float swz(float v) {
    return __int_as_float(__builtin_amdgcn_ds_swizzle(__float_as_int(v), PAT));
}

// xor-merge over q lanes. After D=1,2,4,8 (HALF=8,4,2,1), lane q holds the
// full sum of acc index idx = 8*q0 + 4*q1 + 2*q2 + q3 (q bits).
// Send-only-what-partner-needs: 1 swizzle per pair instead of 2.
template<int D, int HALF>
__device__ __forceinline__ void merge_step(float* acc, bool up) {
    #pragma unroll
    for (int i = 0; i < HALF; ++i) {
        float snd  = up ? acc[i] : acc[i + HALF];
        float keep = up ? acc[i + HALF] : acc[i];
        float rcv  = swz<(D << 10) | 0x1F>(snd);
        acc[i] = keep + rcv;
    }
}

__device__ __forceinline__ float dot4(float4 w, float4 v, float a) {
    a = fmaf(w.x, v.x, a);
    a = fmaf(w.y, v.y, a);
    a = fmaf(w.z, v.z, a);
    a = fmaf(w.w, v.w, a);
    return a;
}

// +4 floats of pad every 32 floats: breaks the 8q/12q power-stride into <=2-way
__device__ __forceinline__ int padk(int k) { return k + 4 * (k >> 5); }

// (sA,sB,sC)=(1,1,0) -> sigmoid(z); (2,2,-1) -> tanh(z) = 2*sigmoid(2z)-1
__device__ __forceinline__ float gate_act(float z, float sA, float sB, float sC) {
    float e = __expf(-z * sA);
    float s = __builtin_amdgcn_rcpf(1.0f + e);
    return fmaf(s, sB, sC);
}

// ---------------------------------------------------------------------------
// Decoder: 256 blocks x 1024 threads, 2 batch rows/block.
// tid = gg*16 + q;  gg in [0,64), q in [0,16).
// Thread: 8 gates {t in i,f,g,o} x {j = gg, gg+64}, k-slice [8q, 8q+8).
// Weights: 16 float4 = 64 VGPRs (no spill). xp precomputed (time-invariant).
// Per step: 128 FMA/thread, 4 ds_read_b128, swizzle merge, 1 barrier.
// ---------------------------------------------------------------------------
__global__ __launch_bounds__(1024)
void dec_kernel(const float* __restrict__ h_enc,  // [B,64]
                const float* __restrict__ Wih,    // [512,64]
                const float* __restrict__ Whh,    // [512,128]
                const float* __restrict__ bias,   // [512]
                float* __restrict__ out)          // [B,T,128]
{
    const int tid = threadIdx.x;
    const int gg  = tid >> 4;
    const int q   = tid & 15;
    const int b0  = blockIdx.x * 2;

    __shared__ __align__(16) float he[2][HDIM];
    __shared__ __align__(16) float hbuf[2][2][DDIM + 16];   // padded rows (144)

    if (tid < 128) {
        int r = tid >> 6, j = tid & 63;
        he[r][j] = h_enc[(size_t)(b0 + r) * HDIM + j];
    }
    {
        float* p = &hbuf[0][0][0];
        for (int i = tid; i < 2 * (DDIM + 16); i += 1024) p[i] = 0.f;
    }

    // recurrent weights -> registers (coalesced float4 loads)
    float4 w[8][2];
    #pragma unroll
    for (int gi = 0; gi < 8; ++gi) {
        int grow = (gi & 3) * DDIM + (gi >> 2) * HDIM + gg;   // t*128 + h2*64 + gg
        const float4* src = (const float4*)(Whh + (size_t)grow * DDIM + 8 * q);
        w[gi][0] = src[0];
        w[gi][1] = src[1];
    }

    const bool u1 = (q & 1), u2 = (q & 2), u4 = (q & 4), u8 = (q & 8);
    // final-lane instance: idx = 8q0+4q1+2q2+q3 -> gi = idx>>1, r = idx&1
    const int t4 = ((q >> 1) & 1) * 2 + ((q >> 2) & 1);  // gate type 0:i 1:f 2:g 3:o
    const int h2 = q & 1;                                // j-half
    const int rr = (q >> 3) & 1;                         // batch row
    const int jj = gg + HDIM * h2;                       // j in [0,128)
    const float sA = (t4 == 2) ? 2.f : 1.f;
    const float sB = sA;
    const float sC = (t4 == 2) ? -1.f : 0.f;
    const bool writer = ((q & 6) == 0);                  // one lane per (jj,rr)

    __syncthreads();

    // xp = bias + Wih_d . h_enc  (time-invariant; same merge layout)
    float xp;
    {
        float acc[16];
        float4 h0 = *(const float4*)(&he[0][4 * q]);
        float4 h1 = *(const float4*)(&he[1][4 * q]);
        #pragma unroll
        for (int gi = 0; gi < 8; ++gi) {
            int grow = (gi & 3) * DDIM + (gi >> 2) * HDIM + gg;
            float4 wv = *(const float4*)(Wih + (size_t)grow * HDIM + 4 * q);
            acc[gi * 2 + 0] = dot4(wv, h0, 0.f);
            acc[gi * 2 + 1] = dot4(wv, h1, 0.f);
        }
        merge_step<1, 8>(acc, u1);
        merge_step<2, 4>(acc, u2);
        merge_step<4, 2>(acc, u4);
        merge_step<8, 1>(acc, u8);
        xp = acc[0] + bias[t4 * DDIM + h2 * HDIM + gg];
    }

    const int rd0 = padk(8 * q);     // contiguous 8 floats in padded space
    const int wj  = padk(jj);
    size_t obase = ((size_t)(b0 + rr) * TT) * DDIM + jj;

    float c_state = 0.f;
    int cb = 0;
    for (int t = 0; t < TT; ++t) {
        float acc[16];
        #pragma unroll
        for (int r = 0; r < 2; ++r) {
            const float* hb = hbuf[cb][r];
            float4 ha = *(const float4*)(hb + rd0);
            float4 hc = *(const float4*)(hb + rd0 + 4);
            #pragma unroll
            for (int gi = 0; gi < 8; ++gi) {
                acc[gi * 2 + r] = dot4(w[gi][1], hc, dot4(w[gi][0], ha, 0.f));
            }
        }
        merge_step<1, 8>(acc, u1);
        merge_step<2, 4>(acc, u2);
        merge_step<4, 2>(acc, u4);
        merge_step<8, 1>(acc, u8);

        float z = acc[0] + xp;
        float v = gate_act(z, sA, sB, sC);
        // gather i,f,g,o across type lanes (preserve bits 0(h2),3(r),4(gg&1))
        float vi = swz<0x19>(v);
        float vf = swz<(4 << 5) | 0x19>(v);
        float vg = swz<(2 << 5) | 0x19>(v);
        float vo = swz<(6 << 5) | 0x19>(v);
        c_state = fmaf(vf, c_state, vi * vg);
        float hv = vo * gate_act(c_state, 2.f, 2.f, -1.f);

        int nb = cb ^ 1;
        if (writer) {
            hbuf[nb][rr][wj] = hv;
            out[obase + (size_t)t * DDIM] = hv;
        }
        __syncthreads();
        cb = nb;
    }
}

// ---------------------------------------------------------------------------
// Encoder: 256 blocks x 512 threads, 2 batch rows/block.
// tid = gg*16 + q;  gg in [0,32), q in [0,16).
// Thread: 8 gates {t} x {j = gg, gg+32}, k-slice [12q, 12q+12) of concat
// [x(128) | h(64)]. Weights: 24 float4 = 96 VGPRs. x double-buffer prefetch.
// ---------------------------------------------------------------------------
__global__ __launch_bounds__(512, 2)
void enc_kernel(const float* __restrict__ x,      // [B,T,128]
                const float* __restrict__ Wih,    // [256,128]
                const float* __restrict__ Whh,    // [256,64]
                const float* __restrict__ bias,   // [256]
                float* __restrict__ h_out)        // [B,64]
{
    const int tid = threadIdx.x;
    const int gg  = tid >> 4;
    const int q   = tid & 15;
    const int b0  = blockIdx.x * 2;

    __shared__ __align__(16) float xh[2][2][DDIM + HDIM + 20];  // padded 212

    float4 w[8][3];
    #pragma unroll
    for (int gi = 0; gi < 8; ++gi) {
        int grow = (gi & 3) * HDIM + (gi >> 2) * 32 + gg;   // t*64 + h2*32 + gg
        #pragma unroll
        for (int c = 0; c < 3; ++c) {
            int k0 = 12 * q + 4 * c;
            const float* src = (k0 < DDIM)
                ? (Wih + (size_t)grow * DDIM + k0)
                : (Whh + (size_t)grow * HDIM + (k0 - DDIM));
            w[gi][c] = *(const float4*)src;
        }
    }

    const bool u1 = (q & 1), u2 = (q & 2), u4 = (q & 4), u8 = (q & 8);
    const int t4 = ((q >> 1) & 1) * 2 + ((q >> 2) & 1);
    const int h2 = q & 1;
    const int rr = (q >> 3) & 1;
    const int jj = gg + 32 * h2;
    const float sA = (t4 == 2) ? 2.f : 1.f;
    const float sB = sA;
    const float sC = (t4 == 2) ? -1.f : 0.f;
    const bool writer = ((q & 6) == 0);
    const float xpc = bias[t4 * HDIM + h2 * 32 + gg];

    const bool stager = (tid < 64);
    const int sr = (tid >> 5) & 1, sc = tid & 31;
    const int psc = padk(4 * sc);
    const int po0 = padk(12 * q), po1 = padk(12 * q + 4), po2 = padk(12 * q + 8);
    const int pwj = padk(DDIM + jj);

    if (stager) {
        float4 xv = *(const float4*)(x + ((size_t)(b0 + sr) * TT + 0) * DDIM + 4 * sc);
        *(float4*)(&xh[0][sr][psc]) = xv;
    }
    if (tid < 128) {
        int r = tid >> 6, j = tid & 63;
        xh[0][r][padk(DDIM + j)] = 0.f;
    }

    float c_state = 0.f;
    __syncthreads();

    int cb = 0;
    for (int t = 0; t < TT; ++t) {
        float4 xnext;
        if (stager) {
            int tload = (t + 1 < TT) ? (t + 1) : (TT - 1);
            xnext = *(const float4*)(x + ((size_t)(b0 + sr) * TT + tload) * DDIM + 4 * sc);
        }

        float acc[16];
        #pragma unroll
        for (int r = 0; r < 2; ++r) {
            const float* xb = xh[cb][r];
            float4 v0 = *(const float4*)(xb + po0);
            float4 v1 = *(const float4*)(xb + po1);
            float4 v2 = *(const float4*)(xb + po2);
            #pragma unroll
            for (int gi = 0; gi < 8; ++gi) {
                acc[gi * 2 + r] =
                    dot4(w[gi][2], v2, dot4(w[gi][1], v1, dot4(w[gi][0], v0, 0.f)));
            }
        }
        merge_step<1, 8>(acc, u1);
        merge_step<2, 4>(acc, u2);
        merge_step<4, 2>(acc, u4);
        merge_step<8, 1>(acc, u8);

        float z = acc[0] + xpc;
        float v = gate_act(z, sA, sB, sC);
        float vi = swz<0x19>(v);
        float vf = swz<(4 << 5) | 0x19>(v);
        float vg = swz<(2 << 5) | 0x19>(v);
        float vo = swz<(6 << 5) | 0x19>(v);
        c_state = fmaf(vf, c_state, vi * vg);
        float hv = vo * gate_act(c_state, 2.f, 2.f, -1.f);

        int nb = cb ^ 1;
        if (writer) xh[nb][rr][pwj] = hv;
        if (stager) *(float4*)(&xh[nb][sr][psc]) = xnext;
        if (t == TT - 1 && writer) h_out[(size_t)(b0 + rr) * HDIM + jj] = hv;
        __syncthreads();
        cb = nb;
    }
}

extern "C" void kernel_launch(void* const* d_in, const int* in_sizes, int n_in,
                              void* d_out, int out_size, void* d_ws, size_t ws_size,
                              hipStream_t stream) {
    const float* x     = (const float*)d_in[0];
    const float* Wih_e = (const float*)d_in[1];
    const float* Whh_e = (const float*)d_in[2];
    const float* b_e   = (const float*)d_in[3];
    const float* Wih_d = (const float*)d_in[4];
    const float* Whh_d = (const float*)d_in[5];
    const float* b_d   = (const float*)d_in[6];
    float* out   = (float*)d_out;
    float* h_enc = (float*)d_ws;   // 512*64 floats = 128 KB scratch

    enc_kernel<<<dim3(256), dim3(512), 0, stream>>>(x, Wih_e, Whh_e, b_e, h_enc);
    dec_kernel<<<dim3(256), dim3(1024), 0, stream>>>(h_enc, Wih_d, Whh_d, b_d, out);
}

// Round 3
// 1290.149 us; speedup vs baseline: 7.2227x; 1.0132x over previous
//
#include <hip/hip_runtime.h>

#define TT 512

typedef float f32x2 __attribute__((ext_vector_type(2)));

// ---- lane data movement -----------------------------------------------------
template<int CTRL>
__device__ __forceinline__ float dpp_mov(float v) {
    return __int_as_float(__builtin_amdgcn_mov_dpp(__float_as_int(v), CTRL, 0xF, 0xF, true));
}
template<int PAT>
__device__ __forceinline__ float swz(float v) {
    return __int_as_float(__builtin_amdgcn_ds_swizzle(__float_as_int(v), PAT));
}

// xor-merge: lane-bit b <-> acc-index bit. After all steps lane q holds acc
// index [b3 b2 b1 b0] = [q0 q1 q2 q3]. D1/D2 run on VALU (DPP quad_perm).
template<int HALF>
__device__ __forceinline__ void merge_d1(float* acc, bool up) {
    #pragma unroll
    for (int i = 0; i < HALF; ++i) {
        float snd  = up ? acc[i] : acc[i + HALF];
        float keep = up ? acc[i + HALF] : acc[i];
        acc[i] = keep + dpp_mov<0xB1>(snd);            // quad_perm xor1
    }
}
template<int HALF>
__device__ __forceinline__ void merge_d2(float* acc, bool up) {
    #pragma unroll
    for (int i = 0; i < HALF; ++i) {
        float snd  = up ? acc[i] : acc[i + HALF];
        float keep = up ? acc[i + HALF] : acc[i];
        acc[i] = keep + dpp_mov<0x4E>(snd);            // quad_perm xor2
    }
}
template<int D, int HALF>
__device__ __forceinline__ void merge_ds(float* acc, bool up) {
    #pragma unroll
    for (int i = 0; i < HALF; ++i) {
        float snd  = up ? acc[i] : acc[i + HALF];
        float keep = up ? acc[i + HALF] : acc[i];
        acc[i] = keep + swz<(D << 10) | 0x1F>(snd);    // ds_swizzle xor D
    }
}

// ---- packed fp32 math -------------------------------------------------------
__device__ __forceinline__ void pk4(f32x2& a, float4 w, float4 v) {
#if __has_builtin(__builtin_elementwise_fma)
    f32x2 w0 = {w.x, w.y}, v0 = {v.x, v.y};
    a = __builtin_elementwise_fma(w0, v0, a);
    f32x2 w1 = {w.z, w.w}, v1 = {v.z, v.w};
    a = __builtin_elementwise_fma(w1, v1, a);
#else
    a.x = fmaf(w.x, v.x, a.x); a.y = fmaf(w.y, v.y, a.y);
    a.x = fmaf(w.z, v.z, a.x); a.y = fmaf(w.w, v.w, a.y);
#endif
}
__device__ __forceinline__ float dot4s(float4 w, float4 v, float a) {
    a = fmaf(w.x, v.x, a); a = fmaf(w.y, v.y, a);
    a = fmaf(w.z, v.z, a); a = fmaf(w.w, v.w, a);
    return a;
}

// (1,1,0) -> sigmoid(z); (2,2,-1) -> tanh(z)
__device__ __forceinline__ float gate_act(float z, float sA, float sB, float sC) {
    float e = __expf(-z * sA);
    float s = __builtin_amdgcn_rcpf(1.0f + e);
    return fmaf(s, sB, sC);
}

// ---------------------------------------------------------------------------
// Decoder: 256 blocks x 1024 threads, 2 batch rows/block.
// tid = gg*16 + q; gg in [0,64), q in [0,16).
// acc idx = t4*4 + h2*2 + r; lane mapping t4=2q0+q1, h2=q2, r=q3.
// Thread k-slice: {4q..4q+3} U {64+4q..64+4q+3} (16B chunks q and q+16:
// 16 addrs x 16B => every bank exactly 2-way => conflict-free).
// Per step: 64 pk_fma, 4 ds_read_b128, 12 DPP + 3 swizzle merge, 1 barrier.
// ---------------------------------------------------------------------------
__global__ __launch_bounds__(1024)
void dec_kernel(const float* __restrict__ h_enc,  // [B,64]
                const float* __restrict__ Wih,    // [512,64]
                const float* __restrict__ Whh,    // [512,128]
                const float* __restrict__ bias,   // [512]
                float* __restrict__ out)          // [B,T,128]
{
    const int tid = threadIdx.x;
    const int gg  = tid >> 4;
    const int q   = tid & 15;
    const int b0  = blockIdx.x * 2;

    __shared__ __align__(16) float he[2][64];
    __shared__ __align__(16) float hbuf[2][2][128];

    if (tid < 128) he[tid >> 6][tid & 63] = h_enc[(size_t)(b0 + (tid >> 6)) * 64 + (tid & 63)];
    if (tid < 256) hbuf[0][tid >> 7][tid & 127] = 0.f;

    // recurrent weights -> registers: w[t4][h2][chunk]
    float4 w[4][2][2];
    #pragma unroll
    for (int t4i = 0; t4i < 4; ++t4i)
        #pragma unroll
        for (int h2i = 0; h2i < 2; ++h2i) {
            const float* base = Whh + (size_t)(t4i * 128 + h2i * 64 + gg) * 128;
            w[t4i][h2i][0] = *(const float4*)(base + 4 * q);
            w[t4i][h2i][1] = *(const float4*)(base + 64 + 4 * q);
        }

    const bool u1 = (q & 1), u2 = (q & 2), u4 = (q & 4), u8 = (q & 8);
    const int t4 = 2 * (q & 1) + ((q >> 1) & 1);   // 0:i 1:f 2:g 3:o
    const int h2 = (q >> 2) & 1;
    const int rr = (q >> 3) & 1;
    const int jj = gg + 64 * h2;
    const float sA = (t4 == 2) ? 2.f : 1.f;
    const float sB = sA;
    const float sC = (t4 == 2) ? -1.f : 0.f;
    const bool writer = ((q & 3) == 0);

    __syncthreads();

    // xp = bias + Wih_d . h_enc (time-invariant)
    float xp;
    {
        float acc[16];
        float4 hv0 = *(const float4*)(&he[0][4 * q]);
        float4 hv1 = *(const float4*)(&he[1][4 * q]);
        #pragma unroll
        for (int t4i = 0; t4i < 4; ++t4i)
            #pragma unroll
            for (int h2i = 0; h2i < 2; ++h2i) {
                float4 wv = *(const float4*)(Wih + (size_t)(t4i * 128 + h2i * 64 + gg) * 64 + 4 * q);
                acc[t4i * 4 + h2i * 2 + 0] = dot4s(wv, hv0, 0.f);
                acc[t4i * 4 + h2i * 2 + 1] = dot4s(wv, hv1, 0.f);
            }
        merge_d1<8>(acc, u1);
        merge_d2<4>(acc, u2);
        merge_ds<4, 2>(acc, u4);
        merge_ds<8, 1>(acc, u8);
        xp = acc[0] + bias[t4 * 128 + h2 * 64 + gg];
    }

    const size_t obase = ((size_t)(b0 + rr) * TT) * 128 + jj;
    float c_state = 0.f;
    int cb = 0;
    for (int t = 0; t < TT; ++t) {
        float acc[16];
        #pragma unroll
        for (int r = 0; r < 2; ++r) {
            const float* hb = hbuf[cb][r];
            float4 ha = *(const float4*)(hb + 4 * q);
            float4 hc = *(const float4*)(hb + 64 + 4 * q);
            #pragma unroll
            for (int t4i = 0; t4i < 4; ++t4i)
                #pragma unroll
                for (int h2i = 0; h2i < 2; ++h2i) {
                    f32x2 a2 = {0.f, 0.f};
                    pk4(a2, w[t4i][h2i][0], ha);
                    pk4(a2, w[t4i][h2i][1], hc);
                    acc[t4i * 4 + h2i * 2 + r] = a2.x + a2.y;
                }
        }
        merge_d1<8>(acc, u1);
        merge_d2<4>(acc, u2);
        merge_ds<4, 2>(acc, u4);
        merge_ds<8, 1>(acc, u8);

        float z = acc[0] + xp;
        float v = gate_act(z, sA, sB, sC);
        // quad lane o holds type t4 = 2*o0+o1: lane0=i, lane1=g, lane2=f, lane3=o
        float vi = dpp_mov<0x00>(v);
        float vg = dpp_mov<0x55>(v);
        float vf = dpp_mov<0xAA>(v);
        float vo = dpp_mov<0xFF>(v);
        c_state = fmaf(vf, c_state, vi * vg);
        float hv = vo * gate_act(c_state, 2.f, 2.f, -1.f);

        int nb = cb ^ 1;
        if (writer) {
            hbuf[nb][rr][jj] = hv;
            out[obase + (size_t)t * 128] = hv;
        }
        __syncthreads();
        cb = nb;
    }
}

// ---------------------------------------------------------------------------
// Encoder: 256 blocks x 512 threads, 2 batch rows/block.
// tid = gg*16 + q; gg in [0,32). Concat k-dim [x(128)|h(64)] = 192.
// Thread k-slice: 16B chunks {q, q+16, q+32}. Same merge/lane mapping as dec.
// ---------------------------------------------------------------------------
__global__ __launch_bounds__(512)
void enc_kernel(const float* __restrict__ x,      // [B,T,128]
                const float* __restrict__ Wih,    // [256,128]
                const float* __restrict__ Whh,    // [256,64]
                const float* __restrict__ bias,   // [256]
                float* __restrict__ h_out)        // [B,64]
{
    const int tid = threadIdx.x;
    const int gg  = tid >> 4;
    const int q   = tid & 15;
    const int b0  = blockIdx.x * 2;

    __shared__ __align__(16) float xh[2][2][192];   // [buf][row][x|h]

    float4 w[4][2][3];
    #pragma unroll
    for (int t4i = 0; t4i < 4; ++t4i)
        #pragma unroll
        for (int h2i = 0; h2i < 2; ++h2i) {
            int grow = t4i * 64 + h2i * 32 + gg;
            w[t4i][h2i][0] = *(const float4*)(Wih + (size_t)grow * 128 + 4 * q);
            w[t4i][h2i][1] = *(const float4*)(Wih + (size_t)grow * 128 + 64 + 4 * q);
            w[t4i][h2i][2] = *(const float4*)(Whh + (size_t)grow * 64 + 4 * q);
        }

    const bool u1 = (q & 1), u2 = (q & 2), u4 = (q & 4), u8 = (q & 8);
    const int t4 = 2 * (q & 1) + ((q >> 1) & 1);
    const int h2 = (q >> 2) & 1;
    const int rr = (q >> 3) & 1;
    const int jj = gg + 32 * h2;
    const float sA = (t4 == 2) ? 2.f : 1.f;
    const float sB = sA;
    const float sC = (t4 == 2) ? -1.f : 0.f;
    const bool writer = ((q & 3) == 0);
    const float xpc = bias[t4 * 64 + h2 * 32 + gg];

    const bool stager = (tid < 64);
    const int sr = (tid >> 5) & 1, sc = tid & 31;

    if (stager)
        *(float4*)(&xh[0][sr][4 * sc]) =
            *(const float4*)(x + ((size_t)(b0 + sr) * TT) * 128 + 4 * sc);
    if (tid < 128) xh[0][tid >> 6][128 + (tid & 63)] = 0.f;

    float c_state = 0.f;
    __syncthreads();

    int cb = 0;
    for (int t = 0; t < TT; ++t) {
        float4 xnext;
        if (stager) {
            int tload = (t + 1 < TT) ? (t + 1) : (TT - 1);
            xnext = *(const float4*)(x + ((size_t)(b0 + sr) * TT + tload) * 128 + 4 * sc);
        }

        float acc[16];
        #pragma unroll
        for (int r = 0; r < 2; ++r) {
            const float* xb = xh[cb][r];
            float4 v0 = *(const float4*)(xb + 4 * q);
            float4 v1 = *(const float4*)(xb + 64 + 4 * q);
            float4 v2 = *(const float4*)(xb + 128 + 4 * q);
            #pragma unroll
            for (int t4i = 0; t4i < 4; ++t4i)
                #pragma unroll
                for (int h2i = 0; h2i < 2; ++h2i) {
                    f32x2 a2 = {0.f, 0.f};
                    pk4(a2, w[t4i][h2i][0], v0);
                    pk4(a2, w[t4i][h2i][1], v1);
                    pk4(a2, w[t4i][h2i][2], v2);
                    acc[t4i * 4 + h2i * 2 + r] = a2.x + a2.y;
                }
        }
        merge_d1<8>(acc, u1);
        merge_d2<4>(acc, u2);
        merge_ds<4, 2>(acc, u4);
        merge_ds<8, 1>(acc, u8);

        float z = acc[0] + xpc;
        float v = gate_act(z, sA, sB, sC);
        float vi = dpp_mov<0x00>(v);
        float vg = dpp_mov<0x55>(v);
        float vf = dpp_mov<0xAA>(v);
        float vo = dpp_mov<0xFF>(v);
        c_state = fmaf(vf, c_state, vi * vg);
        float hv = vo * gate_act(c_state, 2.f, 2.f, -1.f);

        int nb = cb ^ 1;
        if (writer) xh[nb][rr][128 + jj] = hv;
        if (stager) *(float4*)(&xh[nb][sr][4 * sc]) = xnext;
        if (t == TT - 1 && writer) h_out[(size_t)(b0 + rr) * 64 + jj] = hv;
        __syncthreads();
        cb = nb;
    }
}

extern "C" void kernel_launch(void* const* d_in, const int* in_sizes, int n_in,
                              void* d_out, int out_size, void* d_ws, size_t ws_size,
                              hipStream_t stream) {
    const float* x     = (const float*)d_in[0];
    const float* Wih_e = (const float*)d_in[1];
    const float* Whh_e = (const float*)d_in[2];
    const float* b_e   = (const float*)d_in[3];
    const float* Wih_d = (const float*)d_in[4];
    const float* Whh_d = (const float*)d_in[5];
    const float* b_d   = (const float*)d_in[6];
    float* out   = (float*)d_out;
    float* h_enc = (float*)d_ws;

    enc_kernel<<<dim3(256), dim3(512), 0, stream>>>(x, Wih_e, Whh_e, b_e, h_enc);
    dec_kernel<<<dim3(256), dim3(1024), 0, stream>>>(h_enc, Wih_d, Whh_d, b_d, out);
}

// Round 4
// 1044.946 us; speedup vs baseline: 8.9176x; 1.2347x over previous
//
#include <hip/hip_runtime.h>

#define TT 512

typedef float f32x2 __attribute__((ext_vector_type(2)));
typedef float f32x4 __attribute__((ext_vector_type(4)));

template<int CTRL>
__device__ __forceinline__ float dpp_mov(float v) {
    return __int_as_float(__builtin_amdgcn_mov_dpp(__float_as_int(v), CTRL, 0xF, 0xF, true));
}
__device__ __forceinline__ float swz_xor4(float v) {
    return __int_as_float(__builtin_amdgcn_ds_swizzle(__float_as_int(v), 0x101F));
}
// packed fp32 FMA, forced: a = w*v + a
__device__ __forceinline__ void pk(f32x2& a, f32x2 w, f32x2 v) {
    asm("v_pk_fma_f32 %0, %1, %2, %0" : "+v"(a) : "v"(w), "v"(v));
}

// Select-free xor-merge. Lane q (3 bits q0,q1,q2), slot s holds partial of
// output s ^ qt (qt = 4q0+2q1+q2), arranged via permuted weight loading.
// Each level: s[i] += from-partner s[i+H]; partner slot (i+H)^(qt^H) == i^qt.
__device__ __forceinline__ float merge8(float* s) {
    s[0] += dpp_mov<0xB1>(s[4]);   // xor lane-bit0 (quad_perm)
    s[1] += dpp_mov<0xB1>(s[5]);
    s[2] += dpp_mov<0xB1>(s[6]);
    s[3] += dpp_mov<0xB1>(s[7]);
    s[0] += dpp_mov<0x4E>(s[2]);   // xor lane-bit1 (quad_perm)
    s[1] += dpp_mov<0x4E>(s[3]);
    return s[0] + swz_xor4(s[1]);  // xor lane-bit2 (ds_swizzle)
}

// ---------------------------------------------------------------------------
// Decoder: 256 blocks x 1024 threads, 2 batch rows/block.
// tid = gg*8 + q; gg = j in [0,128), q in [0,8) = k-slice id.
// Final owner lane: t4 = 2q0+q1 (0:i 1:f 2:g 3:o), r = q2.
// Weights: 4 rows x 16k = 16 f32x4 = 64 VGPRs. Per step: 8 ds_read_b128,
// 64 v_pk_fma_f32, 7-op merge, quad_perm gate broadcast, 1 barrier.
// LDS h layout: k-slice m at 20*m (8 slices -> 8 distinct bank quads, no
// conflicts; 8-way gg same-address broadcast is free).
// ---------------------------------------------------------------------------
__global__ __launch_bounds__(1024, 4)
void dec_kernel(const float* __restrict__ h_enc,  // [B,64]
                const float* __restrict__ Wih,    // [512,64]
                const float* __restrict__ Whh,    // [512,128]
                const float* __restrict__ bias,   // [512]
                float* __restrict__ out)          // [B,T,128]
{
    const int tid = threadIdx.x;
    const int gg  = tid >> 3;               // j
    const int q   = tid & 7;
    const int q0 = q & 1, q1 = (q >> 1) & 1, q2 = (q >> 2) & 1;
    const int msk2 = (q0 << 1) | q1;
    const int b0  = blockIdx.x * 2;

    __shared__ __align__(16) float he[2][64];
    __shared__ __align__(16) float hb[2][2 * 160];   // [buf][row*160 + padded j]

    if (tid < 128) he[tid >> 6][tid & 63] = h_enc[(size_t)(b0 + (tid >> 6)) * 64 + (tid & 63)];
    if (tid < 256) {
        int r = tid >> 7, j = tid & 127;
        hb[0][r * 160 + j + 4 * (j >> 4)] = 0.f;
    }

    // recurrent weights -> registers (slot-permuted rows: m ^ msk2)
    f32x4 w[4][4];
    #pragma unroll
    for (int m = 0; m < 4; ++m) {
        const float* src = Whh + (size_t)((m ^ msk2) * 128 + gg) * 128 + 16 * q;
        #pragma unroll
        for (int c = 0; c < 4; ++c) w[m][c] = *(const f32x4*)(src + 4 * c);
    }

    const int t4own = 2 * q0 + q1;
    const float sA = (t4own == 2) ? 2.f : 1.f;
    const float sC = (t4own == 2) ? -1.f : 0.f;
    const bool writer = (q0 == 0) && (q1 == 0);
    const int rr  = q2;
    const int oA  = q2 * 160;
    const int oB  = (q2 ^ 1) * 160;
    const int kres = 20 * q;
    const int pwj = q2 * 160 + gg + 4 * (gg >> 4);

    __syncthreads();

    // xp = bias + Wih_d . h_enc (time-invariant; same permuted merge layout)
    float xp;
    {
        const float* heA = he[q2] + 8 * q;
        const float* heB = he[q2 ^ 1] + 8 * q;
        f32x4 hA0 = *(const f32x4*)heA, hA1 = *(const f32x4*)(heA + 4);
        f32x4 hB0 = *(const f32x4*)heB, hB1 = *(const f32x4*)(heB + 4);
        float s[8];
        #pragma unroll
        for (int m = 0; m < 4; ++m) {
            const float* ws = Wih + (size_t)((m ^ msk2) * 128 + gg) * 64 + 8 * q;
            f32x4 w0 = *(const f32x4*)ws, w1 = *(const f32x4*)(ws + 4);
            f32x2 aA = {0.f, 0.f}, aB = {0.f, 0.f};
            pk(aA, w0.lo, hA0.lo); pk(aA, w0.hi, hA0.hi);
            pk(aA, w1.lo, hA1.lo); pk(aA, w1.hi, hA1.hi);
            pk(aB, w0.lo, hB0.lo); pk(aB, w0.hi, hB0.hi);
            pk(aB, w1.lo, hB1.lo); pk(aB, w1.hi, hB1.hi);
            s[2 * m]     = aA.x + aA.y;
            s[2 * m + 1] = aB.x + aB.y;
        }
        xp = merge8(s) + bias[t4own * 128 + gg];
    }

    float c_state = 0.f;
    size_t optr = ((size_t)(b0 + rr) * TT) * 128 + gg;

#define DSTEP(CUR, NXT) {                                                      \
    const float* bAp = (CUR) + oA + kres;                                      \
    const float* bBp = (CUR) + oB + kres;                                      \
    f32x4 ch[4]; f32x2 accA[4], accB[4];                                       \
    _Pragma("unroll") for (int c = 0; c < 4; ++c) ch[c] = *(const f32x4*)(bAp + 4 * c); \
    _Pragma("unroll") for (int m = 0; m < 4; ++m) { f32x2 z2 = {0.f, 0.f};     \
        _Pragma("unroll") for (int c = 0; c < 4; ++c) { pk(z2, w[m][c].lo, ch[c].lo); pk(z2, w[m][c].hi, ch[c].hi); } \
        accA[m] = z2; }                                                        \
    _Pragma("unroll") for (int c = 0; c < 4; ++c) ch[c] = *(const f32x4*)(bBp + 4 * c); \
    _Pragma("unroll") for (int m = 0; m < 4; ++m) { f32x2 z2 = {0.f, 0.f};     \
        _Pragma("unroll") for (int c = 0; c < 4; ++c) { pk(z2, w[m][c].lo, ch[c].lo); pk(z2, w[m][c].hi, ch[c].hi); } \
        accB[m] = z2; }                                                        \
    float s[8];                                                                \
    _Pragma("unroll") for (int m = 0; m < 4; ++m) {                            \
        s[2 * m] = accA[m].x + accA[m].y; s[2 * m + 1] = accB[m].x + accB[m].y; } \
    float z = merge8(s) + xp;                                                  \
    float ez = __expf(-z * sA);                                                \
    float v  = fmaf(__builtin_amdgcn_rcpf(1.0f + ez), sA, sC);                 \
    float vi = dpp_mov<0x00>(v); float vg = dpp_mov<0x55>(v);                  \
    float vf = dpp_mov<0xAA>(v); float vo = dpp_mov<0xFF>(v);                  \
    c_state = fmaf(vf, c_state, vi * vg);                                      \
    float e2 = __expf(-2.f * c_state);                                         \
    float hv = vo * fmaf(__builtin_amdgcn_rcpf(1.f + e2), 2.f, -1.f);          \
    if (writer) { (NXT)[pwj] = hv; out[optr] = hv; }                           \
    optr += 128;                                                               \
    __syncthreads(); }

    #pragma unroll 1
    for (int t = 0; t < TT; t += 2) {
        DSTEP(hb[0], hb[1]);
        DSTEP(hb[1], hb[0]);
    }
#undef DSTEP
}

// ---------------------------------------------------------------------------
// Encoder: 256 blocks x 512 threads, 2 batch rows/block.
// tid = gg*8 + q; gg = j in [0,64). Concat k-dim [x(128)|h(64)] = 192,
// k-slice = 24 floats at padded 28*q (conflict-free). Weights 24 f32x4.
// ---------------------------------------------------------------------------
__global__ __launch_bounds__(512, 2)
void enc_kernel(const float* __restrict__ x,      // [B,T,128]
                const float* __restrict__ Wih,    // [256,128]
                const float* __restrict__ Whh,    // [256,64]
                const float* __restrict__ bias,   // [256]
                float* __restrict__ h_out)        // [B,64]
{
    const int tid = threadIdx.x;
    const int gg  = tid >> 3;               // j in [0,64)
    const int q   = tid & 7;
    const int q0 = q & 1, q1 = (q >> 1) & 1, q2 = (q >> 2) & 1;
    const int msk2 = (q0 << 1) | q1;
    const int b0  = blockIdx.x * 2;

    __shared__ __align__(16) float xh[2][2 * 224];  // [buf][row*224 + padded k]

    f32x4 w[4][6];
    #pragma unroll
    for (int m = 0; m < 4; ++m) {
        int row = (m ^ msk2) * 64 + gg;
        #pragma unroll
        for (int c = 0; c < 6; ++c) {
            int k0 = 24 * q + 4 * c;
            const float* src = (k0 < 128) ? (Wih + (size_t)row * 128 + k0)
                                          : (Whh + (size_t)row * 64 + (k0 - 128));
            w[m][c] = *(const f32x4*)src;
        }
    }

    const int t4own = 2 * q0 + q1;
    const float sA = (t4own == 2) ? 2.f : 1.f;
    const float sC = (t4own == 2) ? -1.f : 0.f;
    const bool writer = (q0 == 0) && (q1 == 0);
    const int rr  = q2;
    const int oA  = q2 * 224;
    const int oB  = (q2 ^ 1) * 224;
    const int kres = 28 * q;
    const int hj  = 128 + gg;
    const int pwj = q2 * 224 + hj + 4 * (hj / 24);
    const float xpc = bias[t4own * 64 + gg];

    const bool stager = (tid < 64);
    const int sr = (tid >> 5) & 1, sc = tid & 31;
    const int psl = sr * 224 + 4 * sc + 4 * ((4 * sc) / 24);
    const float* xbase = x + ((size_t)(b0 + sr) * TT) * 128 + 4 * sc;

    if (stager) *(f32x4*)(&xh[0][psl]) = *(const f32x4*)xbase;
    if (tid < 128) {
        int r = tid >> 6, j = 128 + (tid & 63);
        xh[0][r * 224 + j + 4 * (j / 24)] = 0.f;
    }

    float c_state = 0.f;
    float h_last = 0.f;
    __syncthreads();

#define ESTEP(CUR, NXT, T) {                                                   \
    f32x4 xnext;                                                               \
    if (stager) { int tl = (T) + 1 < TT ? (T) + 1 : TT - 1;                    \
        xnext = *(const f32x4*)(xbase + (size_t)tl * 128); }                   \
    const float* bAp = (CUR) + oA + kres;                                      \
    const float* bBp = (CUR) + oB + kres;                                      \
    f32x4 ch[6]; f32x2 accA[4], accB[4];                                       \
    _Pragma("unroll") for (int c = 0; c < 6; ++c) ch[c] = *(const f32x4*)(bAp + 4 * c); \
    _Pragma("unroll") for (int m = 0; m < 4; ++m) { f32x2 z2 = {0.f, 0.f};     \
        _Pragma("unroll") for (int c = 0; c < 6; ++c) { pk(z2, w[m][c].lo, ch[c].lo); pk(z2, w[m][c].hi, ch[c].hi); } \
        accA[m] = z2; }                                                        \
    _Pragma("unroll") for (int c = 0; c < 6; ++c) ch[c] = *(const f32x4*)(bBp + 4 * c); \
    _Pragma("unroll") for (int m = 0; m < 4; ++m) { f32x2 z2 = {0.f, 0.f};     \
        _Pragma("unroll") for (int c = 0; c < 6; ++c) { pk(z2, w[m][c].lo, ch[c].lo); pk(z2, w[m][c].hi, ch[c].hi); } \
        accB[m] = z2; }                                                        \
    float s[8];                                                                \
    _Pragma("unroll") for (int m = 0; m < 4; ++m) {                            \
        s[2 * m] = accA[m].x + accA[m].y; s[2 * m + 1] = accB[m].x + accB[m].y; } \
    float z = merge8(s) + xpc;                                                 \
    float ez = __expf(-z * sA);                                                \
    float v  = fmaf(__builtin_amdgcn_rcpf(1.0f + ez), sA, sC);                 \
    float vi = dpp_mov<0x00>(v); float vg = dpp_mov<0x55>(v);                  \
    float vf = dpp_mov<0xAA>(v); float vo = dpp_mov<0xFF>(v);                  \
    c_state = fmaf(vf, c_state, vi * vg);                                      \
    float e2 = __expf(-2.f * c_state);                                         \
    float hv = vo * fmaf(__builtin_amdgcn_rcpf(1.f + e2), 2.f, -1.f);          \
    h_last = hv;                                                               \
    if (writer) (NXT)[pwj] = hv;                                               \
    if (stager) *(f32x4*)((NXT) + psl) = xnext;                                \
    __syncthreads(); }

    #pragma unroll 1
    for (int t = 0; t < TT; t += 2) {
        ESTEP(xh[0], xh[1], t);
        ESTEP(xh[1], xh[0], t + 1);
    }
#undef ESTEP

    if (writer) h_out[(size_t)(b0 + rr) * 64 + gg] = h_last;
}

extern "C" void kernel_launch(void* const* d_in, const int* in_sizes, int n_in,
                              void* d_out, int out_size, void* d_ws, size_t ws_size,
                              hipStream_t stream) {
    const float* x     = (const float*)d_in[0];
    const float* Wih_e = (const float*)d_in[1];
    const float* Whh_e = (const float*)d_in[2];
    const float* b_e   = (const float*)d_in[3];
    const float* Wih_d = (const float*)d_in[4];
    const float* Whh_d = (const float*)d_in[5];
    const float* b_d   = (const float*)d_in[6];
    float* out   = (float*)d_out;
    float* h_enc = (float*)d_ws;

    enc_kernel<<<dim3(256), dim3(512), 0, stream>>>(x, Wih_e, Whh_e, b_e, h_enc);
    dec_kernel<<<dim3(256), dim3(1024), 0, stream>>>(h_enc, Wih_d, Whh_d, b_d, out);
}